// Round 4
// baseline (2025.352 us; speedup 1.0000x reference)
//
#include <hip/hip_runtime.h>
#include <hip/hip_bf16.h>

// Problem dims (fixed by reference): D=512, B=32, S_c=256, S_q(T)=32
#define DIMD 512
#define NB   32
#define NS   256
#define NT   32

typedef __bf16 bf16x8 __attribute__((ext_vector_type(8)));
typedef float  f32x4  __attribute__((ext_vector_type(4)));

__device__ __forceinline__ float tanh_fast(float x) {
    float e = __expf(2.f * x);
    return 1.f - 2.f / (e + 1.f);
}

// async global->LDS, 16B per lane; lds dest = wave-uniform base + lane*16
__device__ __forceinline__ void gl_lds16(const __bf16* g, __bf16* l) {
    __builtin_amdgcn_global_load_lds((const __attribute__((address_space(1))) void*)g,
                                     (__attribute__((address_space(3))) void*)l, 16, 0, 0);
}

// ---------------- prep kernels ----------------

// A_cat[b*256+s][0:512]=context[s][b][:], [512:1024]=image[s][b][:]  (fp32 -> bf16)
__global__ void k_prep_acat(const float* __restrict__ ctxin, const float* __restrict__ img,
                            __bf16* __restrict__ acat) {
    int row = blockIdx.x;           // b*256+s
    int b = row >> 8, s = row & 255;
    const float* c  = ctxin + ((size_t)s * NB + b) * DIMD;
    const float* im = img   + ((size_t)s * NB + b) * DIMD;
    __bf16* o = acat + (size_t)row * 1024;
    for (int d = threadIdx.x; d < DIMD; d += 256) {
        o[d]       = (__bf16)c[d];
        o[512 + d] = (__bf16)im[d];
    }
}

__global__ void k_cvt_bf16(const float* __restrict__ in, __bf16* __restrict__ out, int n) {
    for (int i = blockIdx.x * blockDim.x + threadIdx.x; i < n; i += gridDim.x * blockDim.x)
        out[i] = (__bf16)in[i];
}

// dst[c][dOff + r] = src[r][c]  (512x512 fp32 -> bf16 transpose), dst row stride dstStride
__global__ void k_transpose_w(const float* __restrict__ src, __bf16* __restrict__ dst,
                              int dstStride, int dOff) {
    __shared__ float tile[32][33];
    int c0 = blockIdx.x * 32, r0 = blockIdx.y * 32;
    int x = threadIdx.x, y = threadIdx.y;   // x:0..31, y:0..7
#pragma unroll
    for (int k = 0; k < 32; k += 8)
        tile[y + k][x] = src[(size_t)(r0 + y + k) * DIMD + c0 + x];
    __syncthreads();
#pragma unroll
    for (int k = 0; k < 32; k += 8)
        dst[(size_t)(c0 + y + k) * dstStride + dOff + r0 + x] = (__bf16)tile[x][y + k];
}

// ctxT[b][c][s] = ctxb[b*256+s][c]  (bf16 -> bf16), per-batch 256x512 -> 512x256
__global__ void k_transpose_cb(const __bf16* __restrict__ src, __bf16* __restrict__ dst) {
    __shared__ __bf16 tile[32][33];
    int b = blockIdx.z;
    int c0 = blockIdx.x * 32, s0 = blockIdx.y * 32;
    int x = threadIdx.x, y = threadIdx.y;   // 32 x 8
    const __bf16* S = src + (size_t)b * NS * DIMD;
    __bf16* D = dst + (size_t)b * DIMD * NS;
#pragma unroll
    for (int k = 0; k < 32; k += 8)
        tile[y + k][x] = S[(size_t)(s0 + y + k) * DIMD + c0 + x];
    __syncthreads();
#pragma unroll
    for (int k = 0; k < 32; k += 8)
        D[(size_t)(c0 + y + k) * NS + s0 + x] = tile[x][y + k];
}

// ---------------- LDS-staged bf16 MFMA GEMM, 64x64 tile (4 blocks/CU) ----------------
// C[M,N] = A[M,K] * BT[N,K]^T + bias1 (+bias2). 256 thr = 4 waves, wave tile 32x32,
// K-step 64. LDS row-major [row][k], staged via global_load_lds width-16.
__global__ void k_gemm64(const __bf16* __restrict__ A, const __bf16* __restrict__ BT,
                         const float* __restrict__ bias1, const float* __restrict__ bias2,
                         void* __restrict__ out, int M, int N, int K, int out_f32) {
    __shared__ __bf16 As[64 * 64];
    __shared__ __bf16 Bs[64 * 64];
    int tid = threadIdx.x, wave = tid >> 6, lane = tid & 63;
    int wm = wave >> 1, wn = wave & 1;
    int m0 = blockIdx.x * 64, n0 = blockIdx.y * 64;
    int lr = lane & 15, lq = lane >> 4;

    f32x4 acc[2][2];
#pragma unroll
    for (int i = 0; i < 2; i++)
#pragma unroll
        for (int j = 0; j < 2; j++) acc[i][j] = (f32x4){0.f, 0.f, 0.f, 0.f};

    // staging: chunk g = (wave*2+i)*64+lane covers row g>>3, k-eighth g&7 (8 elems)
    int g0 = (wave * 2 + 0) * 64 + lane;
    int g1 = (wave * 2 + 1) * 64 + lane;
    int r0_ = g0 >> 3, c0_ = g0 & 7;
    int r1_ = g1 >> 3, c1_ = g1 & 7;
    __bf16* la0 = As + (wave * 2 + 0) * 512;   // +lane*16B added by HW
    __bf16* la1 = As + (wave * 2 + 1) * 512;
    __bf16* lb0 = Bs + (wave * 2 + 0) * 512;
    __bf16* lb1 = Bs + (wave * 2 + 1) * 512;

    for (int kk = 0; kk < K; kk += 64) {
        gl_lds16(A  + (size_t)(m0 + r0_) * K + kk + c0_ * 8, la0);
        gl_lds16(A  + (size_t)(m0 + r1_) * K + kk + c1_ * 8, la1);
        gl_lds16(BT + (size_t)(n0 + r0_) * K + kk + c0_ * 8, lb0);
        gl_lds16(BT + (size_t)(n0 + r1_) * K + kk + c1_ * 8, lb1);
        __syncthreads();
#pragma unroll
        for (int k2 = 0; k2 < 64; k2 += 32) {
            bf16x8 af[2], bfv[2];
#pragma unroll
            for (int i = 0; i < 2; i++)
                af[i] = *(const bf16x8*)(As + (wm * 32 + i * 16 + lr) * 64 + k2 + lq * 8);
#pragma unroll
            for (int j = 0; j < 2; j++)
                bfv[j] = *(const bf16x8*)(Bs + (wn * 32 + j * 16 + lr) * 64 + k2 + lq * 8);
#pragma unroll
            for (int i = 0; i < 2; i++)
#pragma unroll
                for (int j = 0; j < 2; j++)
                    acc[i][j] = __builtin_amdgcn_mfma_f32_16x16x32_bf16(af[i], bfv[j], acc[i][j], 0, 0, 0);
        }
        __syncthreads();
    }

#pragma unroll
    for (int i = 0; i < 2; i++)
#pragma unroll
        for (int j = 0; j < 2; j++) {
            int col = n0 + wn * 32 + j * 16 + lr;
            float bs = bias1[col] + (bias2 ? bias2[col] : 0.f);
#pragma unroll
            for (int r = 0; r < 4; r++) {
                int row = m0 + wm * 32 + i * 16 + lq * 4 + r;   // verified C/D layout
                float v = acc[i][j][r] + bs;
                if (out_f32) ((float*)out)[(size_t)row * N + col] = v;
                else         ((__bf16*)out)[(size_t)row * N + col] = (__bf16)v;
            }
        }
}

// ---------------- scan: one block per batch, all state in LDS, no inter-block sync ----------------
// 32 blocks x 1024 threads (16 waves/CU). Per t:
//  A) logits: wave w owns rows s=w*16..w*16+15, lane covers 8 consecutive e; tanh+dot+shuffle-reduce
//  B) softmax (exp sums via wave reduce) + weighted ctx sum along contiguous ctxT[b][col][s]
//  C) rm/rrt matvec along contiguous wrmT/wrrT[col][d] (bf16), outputs back to LDS
__global__ __launch_bounds__(1024, 4) void k_scan(
    const __bf16* __restrict__ ctxdm,  // [b*256+s][512]
    const __bf16* __restrict__ ctxT,   // [b][col][s]
    const __bf16* __restrict__ wrmT,   // [col][d]
    const __bf16* __restrict__ wrrT,   // [col][d]
    const float* __restrict__ qmf,     // [t*32+b][512]
    const float* __restrict__ wms, const float* __restrict__ brm,
    const float* __restrict__ brr, float* __restrict__ rout) {
    int b = blockIdx.x;
    int tid = threadIdx.x, wave = tid >> 6, lane = tid & 63;
    int e0 = lane * 8;

    __shared__ float slog[NS];       // logits, then exp() values
    __shared__ float spart[4];       // exp-sum partials
    __shared__ float sps[2][DIMD];   // phase-B half-sums
    __shared__ float srn[DIMD];      // r (current)
    __shared__ float srm[DIMD];      // rm state
    __shared__ float srrt[DIMD];     // tanh(r@W_rr+b_rr) state

    if (tid < DIMD) {
        srm[tid]  = brm[tid];              // r0 = 0
        srrt[tid] = tanh_fast(brr[tid]);
    }
    float wmv[8];
#pragma unroll
    for (int j = 0; j < 8; j++) wmv[j] = wms[e0 + j];
    __syncthreads();

    for (int t = 0; t < NT; t++) {
        // ---- phase A: logits ----
        float rq[8];
        {
            const float* qp = qmf + ((size_t)t * NB + b) * DIMD + e0;
#pragma unroll
            for (int j = 0; j < 8; j++) rq[j] = srm[e0 + j] + qp[j];
        }
#pragma unroll 1
        for (int rr_ = 0; rr_ < 16; rr_++) {
            int s = wave * 16 + rr_;
            bf16x8 cv = *(const bf16x8*)(ctxdm + ((size_t)(b * NS + s)) * DIMD + e0);
            float p_ = 0.f;
#pragma unroll
            for (int j = 0; j < 8; j++)
                p_ += tanh_fast((float)cv[j] + rq[j]) * wmv[j];
#pragma unroll
            for (int off = 32; off; off >>= 1) p_ += __shfl_xor(p_, off);
            if (lane == 0) slog[s] = p_;   // b_ms omitted: softmax shift-invariant
        }
        __syncthreads();   // S1

        // ---- phase B1: exp + sum ----
        float ev = 0.f;
        if (tid < NS) { ev = __expf(slog[tid]); slog[tid] = ev; }
#pragma unroll
        for (int off = 32; off; off >>= 1) ev += __shfl_xor(ev, off);
        if (tid < NS && lane == 0) spart[wave] = ev;
        __syncthreads();   // S2
        float inv = 1.f / (spart[0] + spart[1] + spart[2] + spart[3]);

        // ---- phase B2: weighted ctx sum (2 threads per col, 128 s each) ----
        {
            int h = tid >> 9, col = tid & 511;
            const __bf16* cp = ctxT + ((size_t)b * DIMD + col) * NS + h * 128;
            const float* pp = slog + h * 128;
            float a0 = 0.f, a1 = 0.f;
#pragma unroll 1
            for (int s8 = 0; s8 < 128; s8 += 16) {
                bf16x8 v0 = *(const bf16x8*)(cp + s8);
                bf16x8 v1 = *(const bf16x8*)(cp + s8 + 8);
#pragma unroll
                for (int j = 0; j < 8; j++) {
                    a0 = fmaf(pp[s8 + j],     (float)v0[j], a0);
                    a1 = fmaf(pp[s8 + 8 + j], (float)v1[j], a1);
                }
            }
            sps[h][col] = a0 + a1;
        }
        __syncthreads();   // S3
        if (tid < DIMD) {
            float rn = (sps[0][tid] + sps[1][tid]) * inv + srrt[tid];
            srn[tid] = rn;
            if (t == NT - 1) rout[b * DIMD + tid] = rn;
        }
        __syncthreads();   // S4

        // ---- phase C: rm/rrt matvec (1 thread per output col, contiguous d) ----
        {
            int which = tid >> 9, col = tid & 511;
            const __bf16* wp = (which ? wrrT : wrmT) + (size_t)col * DIMD;
            float a0 = 0.f, a1 = 0.f, a2 = 0.f, a3 = 0.f;
#pragma unroll 1
            for (int d = 0; d < DIMD; d += 32) {
                bf16x8 w0 = *(const bf16x8*)(wp + d);
                bf16x8 w1 = *(const bf16x8*)(wp + d + 8);
                bf16x8 w2 = *(const bf16x8*)(wp + d + 16);
                bf16x8 w3 = *(const bf16x8*)(wp + d + 24);
                const float* sv = srn + d;
#pragma unroll
                for (int j = 0; j < 8; j++) {
                    a0 = fmaf(sv[j],      (float)w0[j], a0);
                    a1 = fmaf(sv[8 + j],  (float)w1[j], a1);
                    a2 = fmaf(sv[16 + j], (float)w2[j], a2);
                    a3 = fmaf(sv[24 + j], (float)w3[j], a3);
                }
            }
            float a = a0 + a1 + a2 + a3;
            if (which == 0) srm[col]  = a + brm[col];
            else            srrt[col] = tanh_fast(a + brr[col]);
        }
        __syncthreads();   // S5
    }
}

// g = r@W_rg + b_rg + qh@W_qg + b_qg   (64 blocks x 256 thr: 8 cols x 32 b each)
__global__ void k_final2(const float* __restrict__ r, const float* __restrict__ qh,
                         const float* __restrict__ Wrg, const float* __restrict__ Wqg,
                         const float* __restrict__ brg, const float* __restrict__ bqg,
                         float* __restrict__ out) {
    int cl = threadIdx.x & 7, b = threadIdx.x >> 3;
    int col = blockIdx.x * 8 + cl;
    const float* rp = r + (size_t)b * DIMD;
    const float* qp = qh + (size_t)b * DIMD;
    float acc = brg[col] + bqg[col];
#pragma unroll 4
    for (int d = 0; d < DIMD; d++)
        acc += rp[d] * Wrg[(size_t)d * DIMD + col] + qp[d] * Wqg[(size_t)d * DIMD + col];
    out[b * DIMD + col] = acc;
}

// ---------------- host ----------------

extern "C" void kernel_launch(void* const* d_in, const int* in_sizes, int n_in,
                              void* d_out, int out_size, void* d_ws, size_t ws_size,
                              hipStream_t stream) {
    const float* ctx_in = (const float*)d_in[0];
    const float* q_in   = (const float*)d_in[1];
    const float* qh     = (const float*)d_in[2];
    const float* img    = (const float*)d_in[3];
    const float* W_fc1  = (const float*)d_in[4];
    const float* b_fc1  = (const float*)d_in[5];
    const float* W_fc2  = (const float*)d_in[6];
    const float* b_fc2  = (const float*)d_in[7];
    const float* W_dm   = (const float*)d_in[8];
    const float* b_dm   = (const float*)d_in[9];
    const float* W_rm   = (const float*)d_in[10];
    const float* b_rm   = (const float*)d_in[11];
    const float* W_qm   = (const float*)d_in[12];
    const float* b_qm   = (const float*)d_in[13];
    const float* W_rr   = (const float*)d_in[14];
    const float* b_rr   = (const float*)d_in[15];
    const float* W_rg   = (const float*)d_in[16];
    const float* b_rg   = (const float*)d_in[17];
    const float* W_qg   = (const float*)d_in[18];
    const float* b_qg   = (const float*)d_in[19];
    const float* W_ms   = (const float*)d_in[20];
    // d_in[21] = b_ms: unused (softmax shift-invariant)

    // workspace layout (~39 MB)
    char* w = (char*)d_ws;
    __bf16* acat  = (__bf16*)w;  w += (size_t)8192 * 1024 * 2;   // 16.78 MB (dead after g1)
    __bf16* qp    = (__bf16*)w;  w += (size_t)1024 * 512 * 2;
    __bf16* wcatT = (__bf16*)w;  w += (size_t)512 * 1024 * 2;
    __bf16* wdmT  = (__bf16*)w;  w += (size_t)512 * 512 * 2;
    __bf16* wqmT  = (__bf16*)w;  w += (size_t)512 * 512 * 2;
    __bf16* ctxb  = (__bf16*)w;  w += (size_t)8192 * 512 * 2;
    __bf16* ctxdm = (__bf16*)w;  w += (size_t)8192 * 512 * 2;
    float*  qmf   = (float*)w;   w += (size_t)1024 * 512 * 4;
    float*  rbuf  = (float*)w;   w += (size_t)NB * DIMD * 4;
    // regions produced AFTER g1 consumed acat -> alias acat (9 MB < 16.78 MB)
    __bf16* ctxT  = acat;                                  // [32][512][256] = 8.39 MB
    __bf16* wrmT  = acat + (size_t)NB * DIMD * NS;         // 0.52 MB
    __bf16* wrrT  = wrmT + (size_t)DIMD * DIMD;            // 0.52 MB

    // prep
    k_prep_acat<<<8192, 256, 0, stream>>>(ctx_in, img, acat);
    k_cvt_bf16<<<512, 256, 0, stream>>>(q_in, qp, NT * NB * DIMD);
    k_transpose_w<<<dim3(16, 16), dim3(32, 8), 0, stream>>>(W_fc1, wcatT, 1024, 0);
    k_transpose_w<<<dim3(16, 16), dim3(32, 8), 0, stream>>>(W_fc2, wcatT, 1024, 512);
    k_transpose_w<<<dim3(16, 16), dim3(32, 8), 0, stream>>>(W_dm, wdmT, 512, 0);
    k_transpose_w<<<dim3(16, 16), dim3(32, 8), 0, stream>>>(W_qm, wqmT, 512, 0);

    // big GEMMs (64x64-tile bf16 MFMA, 4 blocks/CU)
    k_gemm64<<<dim3(128, 8), 256, 0, stream>>>(acat, wcatT, b_fc1, b_fc2, ctxb, 8192, 512, 1024, 0);
    // acat now dead: build scan-layout operands in its place
    k_transpose_w<<<dim3(16, 16), dim3(32, 8), 0, stream>>>(W_rm, wrmT, 512, 0);
    k_transpose_w<<<dim3(16, 16), dim3(32, 8), 0, stream>>>(W_rr, wrrT, 512, 0);
    k_transpose_cb<<<dim3(16, 8, 32), dim3(32, 8), 0, stream>>>(ctxb, ctxT);
    k_gemm64<<<dim3(128, 8), 256, 0, stream>>>(ctxb, wdmT, b_dm, nullptr, ctxdm, 8192, 512, 512, 0);
    k_gemm64<<<dim3(16, 8), 256, 0, stream>>>(qp, wqmT, b_qm, nullptr, qmf, 1024, 512, 512, 1);

    // scan: 32 independent blocks (one per batch), no inter-block sync
    k_scan<<<NB, 1024, 0, stream>>>(ctxdm, ctxT, wrmT, wrrT, qmf, W_ms, b_rm, b_rr, rbuf);

    k_final2<<<64, 256, 0, stream>>>(rbuf, qh, W_rg, W_qg, b_rg, b_qg, (float*)d_out);
}

// Round 5
// 896.090 us; speedup vs baseline: 2.2602x; 2.2602x over previous
//
#include <hip/hip_runtime.h>
#include <hip/hip_bf16.h>

// Problem dims (fixed by reference): D=512, B=32, S_c=256, S_q(T)=32
#define DIMD 512
#define NB   32
#define NS   256
#define NT   32

typedef __bf16 bf16x8 __attribute__((ext_vector_type(8)));
typedef float  f32x4  __attribute__((ext_vector_type(4)));

__device__ __forceinline__ float tanh_fast(float x) {
    float e = __expf(2.f * x);
    return 1.f - 2.f / (e + 1.f);
}

// async global->LDS, 16B per lane; lds dest = wave-uniform base + lane*16
__device__ __forceinline__ void gl_lds16(const __bf16* g, __bf16* l) {
    __builtin_amdgcn_global_load_lds((const __attribute__((address_space(1))) void*)g,
                                     (__attribute__((address_space(3))) void*)l, 16, 0, 0);
}

// ---------------- prep kernels ----------------

__global__ void k_prep_acat(const float* __restrict__ ctxin, const float* __restrict__ img,
                            __bf16* __restrict__ acat) {
    int row = blockIdx.x;           // b*256+s
    int b = row >> 8, s = row & 255;
    const float* c  = ctxin + ((size_t)s * NB + b) * DIMD;
    const float* im = img   + ((size_t)s * NB + b) * DIMD;
    __bf16* o = acat + (size_t)row * 1024;
    for (int d = threadIdx.x; d < DIMD; d += 256) {
        o[d]       = (__bf16)c[d];
        o[512 + d] = (__bf16)im[d];
    }
}

__global__ void k_cvt_bf16(const float* __restrict__ in, __bf16* __restrict__ out, int n) {
    for (int i = blockIdx.x * blockDim.x + threadIdx.x; i < n; i += gridDim.x * blockDim.x)
        out[i] = (__bf16)in[i];
}

// dst[c][dOff + r] = src[r][c]  (512x512 fp32 -> bf16 transpose), dst row stride dstStride
__global__ void k_transpose_w(const float* __restrict__ src, __bf16* __restrict__ dst,
                              int dstStride, int dOff) {
    __shared__ float tile[32][33];
    int c0 = blockIdx.x * 32, r0 = blockIdx.y * 32;
    int x = threadIdx.x, y = threadIdx.y;   // x:0..31, y:0..7
#pragma unroll
    for (int k = 0; k < 32; k += 8)
        tile[y + k][x] = src[(size_t)(r0 + y + k) * DIMD + c0 + x];
    __syncthreads();
#pragma unroll
    for (int k = 0; k < 32; k += 8)
        dst[(size_t)(c0 + y + k) * dstStride + dOff + r0 + x] = (__bf16)tile[x][y + k];
}

// ctxT[b][c][s] = ctxb[b*256+s][c]  (bf16 -> bf16), per-batch 256x512 -> 512x256
__global__ void k_transpose_cb(const __bf16* __restrict__ src, __bf16* __restrict__ dst) {
    __shared__ __bf16 tile[32][33];
    int b = blockIdx.z;
    int c0 = blockIdx.x * 32, s0 = blockIdx.y * 32;
    int x = threadIdx.x, y = threadIdx.y;   // 32 x 8
    const __bf16* S = src + (size_t)b * NS * DIMD;
    __bf16* D = dst + (size_t)b * DIMD * NS;
#pragma unroll
    for (int k = 0; k < 32; k += 8)
        tile[y + k][x] = S[(size_t)(s0 + y + k) * DIMD + c0 + x];
    __syncthreads();
#pragma unroll
    for (int k = 0; k < 32; k += 8)
        D[(size_t)(c0 + y + k) * NS + s0 + x] = tile[x][y + k];
}

// ---------------- LDS-staged bf16 MFMA GEMM, 64x64 tile ----------------
__global__ void k_gemm64(const __bf16* __restrict__ A, const __bf16* __restrict__ BT,
                         const float* __restrict__ bias1, const float* __restrict__ bias2,
                         void* __restrict__ out, int M, int N, int K, int out_f32) {
    __shared__ __bf16 As[64 * 64];
    __shared__ __bf16 Bs[64 * 64];
    int tid = threadIdx.x, wave = tid >> 6, lane = tid & 63;
    int wm = wave >> 1, wn = wave & 1;
    int m0 = blockIdx.x * 64, n0 = blockIdx.y * 64;
    int lr = lane & 15, lq = lane >> 4;

    f32x4 acc[2][2];
#pragma unroll
    for (int i = 0; i < 2; i++)
#pragma unroll
        for (int j = 0; j < 2; j++) acc[i][j] = (f32x4){0.f, 0.f, 0.f, 0.f};

    int g0 = (wave * 2 + 0) * 64 + lane;
    int g1 = (wave * 2 + 1) * 64 + lane;
    int r0_ = g0 >> 3, c0_ = g0 & 7;
    int r1_ = g1 >> 3, c1_ = g1 & 7;
    __bf16* la0 = As + (wave * 2 + 0) * 512;
    __bf16* la1 = As + (wave * 2 + 1) * 512;
    __bf16* lb0 = Bs + (wave * 2 + 0) * 512;
    __bf16* lb1 = Bs + (wave * 2 + 1) * 512;

    for (int kk = 0; kk < K; kk += 64) {
        gl_lds16(A  + (size_t)(m0 + r0_) * K + kk + c0_ * 8, la0);
        gl_lds16(A  + (size_t)(m0 + r1_) * K + kk + c1_ * 8, la1);
        gl_lds16(BT + (size_t)(n0 + r0_) * K + kk + c0_ * 8, lb0);
        gl_lds16(BT + (size_t)(n0 + r1_) * K + kk + c1_ * 8, lb1);
        __syncthreads();
#pragma unroll
        for (int k2 = 0; k2 < 64; k2 += 32) {
            bf16x8 af[2], bfv[2];
#pragma unroll
            for (int i = 0; i < 2; i++)
                af[i] = *(const bf16x8*)(As + (wm * 32 + i * 16 + lr) * 64 + k2 + lq * 8);
#pragma unroll
            for (int j = 0; j < 2; j++)
                bfv[j] = *(const bf16x8*)(Bs + (wn * 32 + j * 16 + lr) * 64 + k2 + lq * 8);
#pragma unroll
            for (int i = 0; i < 2; i++)
#pragma unroll
                for (int j = 0; j < 2; j++)
                    acc[i][j] = __builtin_amdgcn_mfma_f32_16x16x32_bf16(af[i], bfv[j], acc[i][j], 0, 0, 0);
        }
        __syncthreads();
    }

#pragma unroll
    for (int i = 0; i < 2; i++)
#pragma unroll
        for (int j = 0; j < 2; j++) {
            int col = n0 + wn * 32 + j * 16 + lr;
            float bs = bias1[col] + (bias2 ? bias2[col] : 0.f);
#pragma unroll
            for (int r = 0; r < 4; r++) {
                int row = m0 + wm * 32 + i * 16 + lq * 4 + r;
                float v = acc[i][j][r] + bs;
                if (out_f32) ((float*)out)[(size_t)row * N + col] = v;
                else         ((__bf16*)out)[(size_t)row * N + col] = (__bf16)v;
            }
        }
}

// ---------------- scan: 8 blocks/batch, fence-free flag sync ----------------

// Per-batch 8-block barrier: NO acquire/release fences (they emit buffer_inv /
// buffer_wbl2 -> round-3's 23us/barrier disaster). All cross-block data moves
// via RELAXED agent atomics (uncached, straight to coherence point); ordering:
// __syncthreads drains vmcnt(0) in every wave (stores at CP), belt-and-
// suspenders explicit vmcnt(0), then RELAXED arrive-RMW; consumer polls
// RELAXED in thread 0 only.
__device__ __forceinline__ void bbar(unsigned* c) {
    __syncthreads();                       // drains vmcnt(0) per wave
    if (threadIdx.x == 0) {
        __atomic_signal_fence(__ATOMIC_SEQ_CST);
        __builtin_amdgcn_s_waitcnt(0x0F70);   // vmcnt(0) only
        __atomic_signal_fence(__ATOMIC_SEQ_CST);
        __hip_atomic_fetch_add(c, 1u, __ATOMIC_RELAXED, __HIP_MEMORY_SCOPE_AGENT);
        while (__hip_atomic_load(c, __ATOMIC_RELAXED, __HIP_MEMORY_SCOPE_AGENT) < 8u)
            __builtin_amdgcn_s_sleep(1);
        __atomic_signal_fence(__ATOMIC_SEQ_CST);
    }
    __syncthreads();
}

// grid 256 = 32 batches x 8 slices; block 512 threads (8 waves).
// Block (b,j) owns e-slice/col-slice [j*64,(j+1)*64). Per step t:
//  A : partial logits over own e-slice (tanh linear-split over e)  -> publish
//  bar1
//  B1: gather partials, softmax, r-slice = sum_s p*ctxT + h_own    -> publish r
//  bar2
//  B2: gather full r, matvec slices -> rm-slice, h-slice (block-local LDS)
__global__ __launch_bounds__(512) void k_scan(
    const __bf16* __restrict__ ctxdm,  // [b*256+s][512]
    const __bf16* __restrict__ ctxT,   // [b][c][s]
    const __bf16* __restrict__ wrmT,   // [c][d]
    const __bf16* __restrict__ wrrT,   // [c][d]
    const float* __restrict__ qmf,     // [t*32+b][512]
    const float* __restrict__ wms, const float* __restrict__ brm,
    const float* __restrict__ brr,
    float* partials,                   // [b][8][256]
    float* rpub,                       // [b][512]
    unsigned* ctr,                     // [2][NT][NB], zeroed
    float* __restrict__ rbuf) {
    int bid = blockIdx.x;
    int b = bid >> 3, j = bid & 7;
    int tid = threadIdx.x, wave = tid >> 6, lane = tid & 63;
    int g = lane >> 3, i = lane & 7;       // s-subgroup, e-chunk
    int e0 = j * 64 + i * 8;

    __shared__ float spart[NS];
    __shared__ float sp[NS];
    __shared__ float sq[512];
    __shared__ float s4[4];
    __shared__ float srm[64], sh[64];
    __shared__ float sr[512];
    __shared__ float smv[512];

    if (tid < 64) {
        srm[tid] = brm[j * 64 + tid];            // rm_0 slice (r0 = 0)
        sh[tid]  = tanh_fast(brr[j * 64 + tid]); // h_0 slice
    }
    float wm[8];
#pragma unroll
    for (int u = 0; u < 8; u++) wm[u] = wms[e0 + u];
    __syncthreads();

    for (int t = 0; t < NT; t++) {
        // ---- phase A: partial logits over e-slice ----
        float rq[8];
        {
            const float* qp = qmf + ((size_t)t * NB + b) * DIMD + e0;
#pragma unroll
            for (int u = 0; u < 8; u++) rq[u] = srm[i * 8 + u] + qp[u];
        }
#pragma unroll
        for (int k = 0; k < 4; k++) {
            int s = wave * 32 + k * 8 + g;
            bf16x8 cv = *(const bf16x8*)(ctxdm + ((size_t)(b * NS + s)) * DIMD + e0);
            float a = 0.f;
#pragma unroll
            for (int u = 0; u < 8; u++)
                a += tanh_fast((float)cv[u] + rq[u]) * wm[u];
            a += __shfl_xor(a, 1); a += __shfl_xor(a, 2); a += __shfl_xor(a, 4);
            if (i == 0) spart[s] = a;
        }
        __syncthreads();
        __atomic_signal_fence(__ATOMIC_SEQ_CST);
        if (tid < NS)
            __hip_atomic_store(&partials[(b * 8 + j) * NS + tid], spart[tid],
                               __ATOMIC_RELAXED, __HIP_MEMORY_SCOPE_AGENT);
        __atomic_signal_fence(__ATOMIC_SEQ_CST);
        bbar(&ctr[(0 * NT + t) * NB + b]);

        // ---- phase B1: gather partials, softmax, r-slice ----
        {
            int s = tid >> 1, jh = (tid & 1) * 4;
            float a = 0.f;
#pragma unroll
            for (int u = 0; u < 4; u++)
                a += __hip_atomic_load(&partials[(b * 8 + jh + u) * NS + s],
                                       __ATOMIC_RELAXED, __HIP_MEMORY_SCOPE_AGENT);
            sq[tid] = a;
        }
        __syncthreads();
        float ev = 0.f;
        if (tid < NS) { ev = __expf(sq[2 * tid] + sq[2 * tid + 1]); sp[tid] = ev; }
#pragma unroll
        for (int off = 32; off; off >>= 1) ev += __shfl_xor(ev, off);
        if (tid < NS && lane == 0) s4[wave] = ev;
        __syncthreads();   // also separates sq reads from sq reuse below
        float inv = 1.f / (s4[0] + s4[1] + s4[2] + s4[3]);
        {
            int cl = tid >> 3, q = tid & 7;
            const __bf16* cp = ctxT + ((size_t)(b * DIMD) + j * 64 + cl) * NS + q * 32;
            const float* pp = sp + q * 32;
            float a = 0.f;
#pragma unroll
            for (int s8 = 0; s8 < 32; s8 += 8) {
                bf16x8 v = *(const bf16x8*)(cp + s8);
#pragma unroll
                for (int u = 0; u < 8; u++) a = fmaf(pp[s8 + u], (float)v[u], a);
            }
            sq[tid] = a;
        }
        __syncthreads();
        if (tid < 64) {
            float a = 0.f;
#pragma unroll
            for (int u = 0; u < 8; u++) a += sq[tid * 8 + u];
            float rv = a * inv + sh[tid];
            if (t == NT - 1) rbuf[b * DIMD + j * 64 + tid] = rv;   // final r
            else
                __hip_atomic_store(&rpub[b * DIMD + j * 64 + tid], rv,
                                   __ATOMIC_RELAXED, __HIP_MEMORY_SCOPE_AGENT);
        }
        __atomic_signal_fence(__ATOMIC_SEQ_CST);
        if (t == NT - 1) break;            // no consumers after last step
        bbar(&ctr[(1 * NT + t) * NB + b]);

        // ---- phase B2: gather r, matvec slices -> rm/h (block-local) ----
        sr[tid] = __hip_atomic_load(&rpub[b * DIMD + tid],
                                    __ATOMIC_RELAXED, __HIP_MEMORY_SCOPE_AGENT);
        __syncthreads();
        {
            int m = tid >> 8, cl = (tid >> 2) & 63, q = tid & 3;
            const __bf16* wp = (m ? wrrT : wrmT) + ((size_t)(j * 64 + cl)) * DIMD + q * 128;
            const float* sv = sr + q * 128;
            float a0 = 0.f, a1 = 0.f;
#pragma unroll 4
            for (int d = 0; d < 128; d += 16) {
                bf16x8 w0 = *(const bf16x8*)(wp + d);
                bf16x8 w1 = *(const bf16x8*)(wp + d + 8);
#pragma unroll
                for (int u = 0; u < 8; u++) {
                    a0 = fmaf(sv[d + u],     (float)w0[u], a0);
                    a1 = fmaf(sv[d + 8 + u], (float)w1[u], a1);
                }
            }
            smv[tid] = a0 + a1;
        }
        __syncthreads();
        if (tid < 128) {
            int m = tid >> 6, cl = tid & 63;
            float a = smv[m * 256 + cl * 4] + smv[m * 256 + cl * 4 + 1]
                    + smv[m * 256 + cl * 4 + 2] + smv[m * 256 + cl * 4 + 3];
            int col = j * 64 + cl;
            if (m == 0) srm[cl] = a + brm[col];
            else        sh[cl]  = tanh_fast(a + brr[col]);
        }
        __syncthreads();
    }
}

// g = r@W_rg + b_rg + qh@W_qg + b_qg   (64 blocks x 256 thr)
__global__ void k_final2(const float* __restrict__ r, const float* __restrict__ qh,
                         const float* __restrict__ Wrg, const float* __restrict__ Wqg,
                         const float* __restrict__ brg, const float* __restrict__ bqg,
                         float* __restrict__ out) {
    int cl = threadIdx.x & 7, b = threadIdx.x >> 3;
    int col = blockIdx.x * 8 + cl;
    const float* rp = r + (size_t)b * DIMD;
    const float* qp = qh + (size_t)b * DIMD;
    float acc = brg[col] + bqg[col];
#pragma unroll 4
    for (int d = 0; d < DIMD; d++)
        acc += rp[d] * Wrg[(size_t)d * DIMD + col] + qp[d] * Wqg[(size_t)d * DIMD + col];
    out[b * DIMD + col] = acc;
}

// ---------------- host ----------------

extern "C" void kernel_launch(void* const* d_in, const int* in_sizes, int n_in,
                              void* d_out, int out_size, void* d_ws, size_t ws_size,
                              hipStream_t stream) {
    const float* ctx_in = (const float*)d_in[0];
    const float* q_in   = (const float*)d_in[1];
    const float* qh     = (const float*)d_in[2];
    const float* img    = (const float*)d_in[3];
    const float* W_fc1  = (const float*)d_in[4];
    const float* b_fc1  = (const float*)d_in[5];
    const float* W_fc2  = (const float*)d_in[6];
    const float* b_fc2  = (const float*)d_in[7];
    const float* W_dm   = (const float*)d_in[8];
    const float* b_dm   = (const float*)d_in[9];
    const float* W_rm   = (const float*)d_in[10];
    const float* b_rm   = (const float*)d_in[11];
    const float* W_qm   = (const float*)d_in[12];
    const float* b_qm   = (const float*)d_in[13];
    const float* W_rr   = (const float*)d_in[14];
    const float* b_rr   = (const float*)d_in[15];
    const float* W_rg   = (const float*)d_in[16];
    const float* b_rg   = (const float*)d_in[17];
    const float* W_qg   = (const float*)d_in[18];
    const float* b_qg   = (const float*)d_in[19];
    const float* W_ms   = (const float*)d_in[20];
    // d_in[21] = b_ms: unused (softmax shift-invariant)

    // workspace layout (~37.7 MB peak; proven budget 38.9 MB)
    char* w = (char*)d_ws;
    __bf16* acat  = (__bf16*)w;  w += (size_t)8192 * 1024 * 2;   // 16.78 MB, dead after g1
    __bf16* qp    = (__bf16*)w;  w += (size_t)1024 * 512 * 2;
    __bf16* wcatT = (__bf16*)w;  w += (size_t)512 * 1024 * 2;
    __bf16* wdmT  = (__bf16*)w;  w += (size_t)512 * 512 * 2;
    __bf16* wqmT  = (__bf16*)w;  w += (size_t)512 * 512 * 2;
    __bf16* wrmT2 = (__bf16*)w;  w += (size_t)512 * 512 * 2;
    __bf16* wrrT2 = (__bf16*)w;  w += (size_t)512 * 512 * 2;
    __bf16* ctxb  = (__bf16*)w;  w += (size_t)8192 * 512 * 2;
    __bf16* ctxdm = (__bf16*)w;  w += (size_t)8192 * 512 * 2;
    // sub-allocate dead acat region (written only after g1 consumed it)
    char* x = (char*)acat;
    __bf16*   ctxT  = (__bf16*)x;    x += (size_t)NB * DIMD * NS * 2;  // 8.39 MB
    float*    qmf   = (float*)x;     x += (size_t)1024 * 512 * 4;      // 2.10 MB
    float*    rpub  = (float*)x;     x += (size_t)NB * DIMD * 4;       // 64 KB
    float*    parts = (float*)x;     x += (size_t)NB * 8 * NS * 4;     // 256 KB
    float*    rbuf  = (float*)x;     x += (size_t)NB * DIMD * 4;       // 64 KB
    unsigned* ctr   = (unsigned*)x;  x += (size_t)2 * NT * NB * 4;     // 8 KB

    // prep (acat whole-region writes happen first)
    k_prep_acat<<<8192, 256, 0, stream>>>(ctx_in, img, acat);
    k_cvt_bf16<<<512, 256, 0, stream>>>(q_in, qp, NT * NB * DIMD);
    k_transpose_w<<<dim3(16, 16), dim3(32, 8), 0, stream>>>(W_fc1, wcatT, 1024, 0);
    k_transpose_w<<<dim3(16, 16), dim3(32, 8), 0, stream>>>(W_fc2, wcatT, 1024, 512);
    k_transpose_w<<<dim3(16, 16), dim3(32, 8), 0, stream>>>(W_dm, wdmT, 512, 0);
    k_transpose_w<<<dim3(16, 16), dim3(32, 8), 0, stream>>>(W_qm, wqmT, 512, 0);
    k_transpose_w<<<dim3(16, 16), dim3(32, 8), 0, stream>>>(W_rm, wrmT2, 512, 0);
    k_transpose_w<<<dim3(16, 16), dim3(32, 8), 0, stream>>>(W_rr, wrrT2, 512, 0);

    // g1: ctx_cat -> ctxb (consumes acat)
    k_gemm64<<<dim3(128, 8), 256, 0, stream>>>(acat, wcatT, b_fc1, b_fc2, ctxb, 8192, 512, 1024, 0);
    // acat dead: build scan operands in its place
    k_transpose_cb<<<dim3(16, 8, 32), dim3(32, 8), 0, stream>>>(ctxb, ctxT);
    k_gemm64<<<dim3(128, 8), 256, 0, stream>>>(ctxb, wdmT, b_dm, nullptr, ctxdm, 8192, 512, 512, 0);
    k_gemm64<<<dim3(16, 8), 256, 0, stream>>>(qp, wqmT, b_qm, nullptr, qmf, 1024, 512, 512, 1);

    // zero barrier counters (ws is 0xAA-poisoned before every launch)
    hipMemsetAsync(ctr, 0, (size_t)2 * NT * NB * 4, stream);

    // full-machine scan: 256 blocks (8 per batch) x 512 threads
    k_scan<<<256, 512, 0, stream>>>(ctxdm, ctxT, wrmT2, wrrT2, qmf, W_ms,
                                    b_rm, b_rr, parts, rpub, ctr, rbuf);

    k_final2<<<64, 256, 0, stream>>>(rbuf, qh, W_rg, W_qg, b_rg, b_qg, (float*)d_out);
}

// Round 6
// 779.259 us; speedup vs baseline: 2.5991x; 1.1499x over previous
//
#include <hip/hip_runtime.h>
#include <hip/hip_bf16.h>

// Problem dims (fixed by reference): D=512, B=32, S_c=256, S_q(T)=32
#define DIMD 512
#define NB   32
#define NS   256
#define NT   32

typedef __bf16 bf16x8 __attribute__((ext_vector_type(8)));
typedef float  f32x4  __attribute__((ext_vector_type(4)));

__device__ __forceinline__ float tanh_fast(float x) {
    float e = __expf(2.f * x);
    return 1.f - 2.f / (e + 1.f);
}

// async global->LDS, 16B per lane; lds dest = wave-uniform base + lane*16
__device__ __forceinline__ void gl_lds16(const __bf16* g, __bf16* l) {
    __builtin_amdgcn_global_load_lds((const __attribute__((address_space(1))) void*)g,
                                     (__attribute__((address_space(3))) void*)l, 16, 0, 0);
}

// ---------------- prep kernels ----------------

__global__ void k_prep_acat(const float* __restrict__ ctxin, const float* __restrict__ img,
                            __bf16* __restrict__ acat) {
    int row = blockIdx.x;           // b*256+s
    int b = row >> 8, s = row & 255;
    const float* c  = ctxin + ((size_t)s * NB + b) * DIMD;
    const float* im = img   + ((size_t)s * NB + b) * DIMD;
    __bf16* o = acat + (size_t)row * 1024;
    for (int d = threadIdx.x; d < DIMD; d += 256) {
        o[d]       = (__bf16)c[d];
        o[512 + d] = (__bf16)im[d];
    }
}

__global__ void k_cvt_bf16(const float* __restrict__ in, __bf16* __restrict__ out, int n) {
    for (int i = blockIdx.x * blockDim.x + threadIdx.x; i < n; i += gridDim.x * blockDim.x)
        out[i] = (__bf16)in[i];
}

// fused transpose of the six 512x512 weight matrices (fp32 -> bf16), z selects
__global__ void k_transpose_w6(const float* __restrict__ s0, const float* __restrict__ s1,
                               const float* __restrict__ s2, const float* __restrict__ s3,
                               const float* __restrict__ s4_, const float* __restrict__ s5,
                               __bf16* __restrict__ d01, __bf16* __restrict__ d2,
                               __bf16* __restrict__ d3, __bf16* __restrict__ d4,
                               __bf16* __restrict__ d5) {
    __shared__ float tile[32][33];
    int z = blockIdx.z;
    const float* src = (z == 0) ? s0 : (z == 1) ? s1 : (z == 2) ? s2
                     : (z == 3) ? s3 : (z == 4) ? s4_ : s5;
    __bf16* dst; int stride, off;
    if (z < 2) { dst = d01; stride = 1024; off = z * 512; }
    else {
        dst = (z == 2) ? d2 : (z == 3) ? d3 : (z == 4) ? d4 : d5;
        stride = 512; off = 0;
    }
    int c0 = blockIdx.x * 32, r0 = blockIdx.y * 32;
    int x = threadIdx.x, y = threadIdx.y;   // 32 x 8
#pragma unroll
    for (int k = 0; k < 32; k += 8)
        tile[y + k][x] = src[(size_t)(r0 + y + k) * DIMD + c0 + x];
    __syncthreads();
#pragma unroll
    for (int k = 0; k < 32; k += 8)
        dst[(size_t)(c0 + y + k) * stride + off + r0 + x] = (__bf16)tile[x][y + k];
}

// ctxT[b][c][s] = ctxb[b*256+s][c]  (bf16 -> bf16), per-batch 256x512 -> 512x256
__global__ void k_transpose_cb(const __bf16* __restrict__ src, __bf16* __restrict__ dst) {
    __shared__ __bf16 tile[32][33];
    int b = blockIdx.z;
    int c0 = blockIdx.x * 32, s0 = blockIdx.y * 32;
    int x = threadIdx.x, y = threadIdx.y;   // 32 x 8
    const __bf16* S = src + (size_t)b * NS * DIMD;
    __bf16* D = dst + (size_t)b * DIMD * NS;
#pragma unroll
    for (int k = 0; k < 32; k += 8)
        tile[y + k][x] = S[(size_t)(s0 + y + k) * DIMD + c0 + x];
    __syncthreads();
#pragma unroll
    for (int k = 0; k < 32; k += 8)
        D[(size_t)(c0 + y + k) * NS + s0 + x] = tile[x][y + k];
}

// ---------------- LDS-staged bf16 MFMA GEMM, 64x64 tile ----------------
__global__ void k_gemm64(const __bf16* __restrict__ A, const __bf16* __restrict__ BT,
                         const float* __restrict__ bias1, const float* __restrict__ bias2,
                         void* __restrict__ out, int M, int N, int K, int out_f32) {
    __shared__ __bf16 As[64 * 64];
    __shared__ __bf16 Bs[64 * 64];
    int tid = threadIdx.x, wave = tid >> 6, lane = tid & 63;
    int wm = wave >> 1, wn = wave & 1;
    int m0 = blockIdx.x * 64, n0 = blockIdx.y * 64;
    int lr = lane & 15, lq = lane >> 4;

    f32x4 acc[2][2];
#pragma unroll
    for (int i = 0; i < 2; i++)
#pragma unroll
        for (int j = 0; j < 2; j++) acc[i][j] = (f32x4){0.f, 0.f, 0.f, 0.f};

    int g0 = (wave * 2 + 0) * 64 + lane;
    int g1 = (wave * 2 + 1) * 64 + lane;
    int r0_ = g0 >> 3, c0_ = g0 & 7;
    int r1_ = g1 >> 3, c1_ = g1 & 7;
    __bf16* la0 = As + (wave * 2 + 0) * 512;
    __bf16* la1 = As + (wave * 2 + 1) * 512;
    __bf16* lb0 = Bs + (wave * 2 + 0) * 512;
    __bf16* lb1 = Bs + (wave * 2 + 1) * 512;

    for (int kk = 0; kk < K; kk += 64) {
        gl_lds16(A  + (size_t)(m0 + r0_) * K + kk + c0_ * 8, la0);
        gl_lds16(A  + (size_t)(m0 + r1_) * K + kk + c1_ * 8, la1);
        gl_lds16(BT + (size_t)(n0 + r0_) * K + kk + c0_ * 8, lb0);
        gl_lds16(BT + (size_t)(n0 + r1_) * K + kk + c1_ * 8, lb1);
        __syncthreads();
#pragma unroll
        for (int k2 = 0; k2 < 64; k2 += 32) {
            bf16x8 af[2], bfv[2];
#pragma unroll
            for (int i = 0; i < 2; i++)
                af[i] = *(const bf16x8*)(As + (wm * 32 + i * 16 + lr) * 64 + k2 + lq * 8);
#pragma unroll
            for (int j = 0; j < 2; j++)
                bfv[j] = *(const bf16x8*)(Bs + (wn * 32 + j * 16 + lr) * 64 + k2 + lq * 8);
#pragma unroll
            for (int i = 0; i < 2; i++)
#pragma unroll
                for (int j = 0; j < 2; j++)
                    acc[i][j] = __builtin_amdgcn_mfma_f32_16x16x32_bf16(af[i], bfv[j], acc[i][j], 0, 0, 0);
        }
        __syncthreads();
    }

#pragma unroll
    for (int i = 0; i < 2; i++)
#pragma unroll
        for (int j = 0; j < 2; j++) {
            int col = n0 + wn * 32 + j * 16 + lr;
            float bs = bias1[col] + (bias2 ? bias2[col] : 0.f);
#pragma unroll
            for (int r = 0; r < 4; r++) {
                int row = m0 + wm * 32 + i * 16 + lq * 4 + r;
                float v = acc[i][j][r] + bs;
                if (out_f32) ((float*)out)[(size_t)row * N + col] = v;
                else         ((__bf16*)out)[(size_t)row * N + col] = (__bf16)v;
            }
        }
}

// ---------------- scan: 8 blocks/batch, fence-free flag sync, on-chip state ----------------

// Fence-free per-batch 8-block barrier (see round-5 notes: ACQUIRE/RELEASE agent
// fences emit buffer_inv/wbl2 -> 23us/barrier; RELAXED uncached atomics at the
// coherence point + vmcnt drain from __syncthreads give correct ordering).
__device__ __forceinline__ void bbar(unsigned* c) {
    __syncthreads();                       // drains vmcnt(0) per wave
    if (threadIdx.x == 0) {
        __atomic_signal_fence(__ATOMIC_SEQ_CST);
        __builtin_amdgcn_s_waitcnt(0x0F70);   // vmcnt(0) only
        __atomic_signal_fence(__ATOMIC_SEQ_CST);
        __hip_atomic_fetch_add(c, 1u, __ATOMIC_RELAXED, __HIP_MEMORY_SCOPE_AGENT);
        while (__hip_atomic_load(c, __ATOMIC_RELAXED, __HIP_MEMORY_SCOPE_AGENT) < 8u)
            __builtin_amdgcn_s_sleep(1);
        __atomic_signal_fence(__ATOMIC_SEQ_CST);
    }
    __syncthreads();
}

// grid 256 = 32 batches x 8 slices; block 512 threads (8 waves), 1 block/CU.
// Loop-invariant data staged ONCE: ctxdm slice + ctxT slice + qm slices in LDS,
// weight slice in 64 VGPRs/thread. Per-step global traffic = partials/r atomics only.
__global__ __launch_bounds__(512, 2) void k_scan(
    const __bf16* __restrict__ ctxdm,  // [b*256+s][512]
    const __bf16* __restrict__ ctxT,   // [b][c][s]
    const __bf16* __restrict__ wrmT,   // [c][d]
    const __bf16* __restrict__ wrrT,   // [c][d]
    const float* __restrict__ qmf,     // [t*32+b][512]
    const float* __restrict__ wms, const float* __restrict__ brm,
    const float* __restrict__ brr,
    float* partials,                   // [b][8][256]
    float* rpub,                       // [b][512]
    unsigned* ctr,                     // [2][NT][NB], zeroed
    float* __restrict__ rbuf) {
    int bid = blockIdx.x;
    int b = bid >> 3, j = bid & 7;
    int tid = threadIdx.x, wave = tid >> 6, lane = tid & 63;
    int g = lane >> 3, i = lane & 7;       // s-subgroup, e-chunk
    int e0 = j * 64 + i * 8;

    __shared__ __bf16 sA[256 * 72];    // ctxdm slice, row stride 72 (pad kills 8-way conflicts)
    __shared__ __bf16 sCT[64 * 264];   // ctxT slice, row stride 264
    __shared__ float  sQ[NT * 64];     // qm e-slice for all t
    __shared__ float  spart[NS];
    __shared__ float  sp[NS];
    __shared__ float  sq[512];
    __shared__ float  s4[4];
    __shared__ float  srm[64], sh[64];
    __shared__ float  sr[512];
    __shared__ float  smv[512];

    // ---- one-time staging ----
    for (int c = tid; c < 2048; c += 512) {            // sA: 256 rows x 64 e
        int row = c >> 3, c8 = c & 7;
        *(bf16x8*)(sA + row * 72 + c8 * 8) =
            *(const bf16x8*)(ctxdm + ((size_t)(b * NS + row)) * DIMD + j * 64 + c8 * 8);
    }
    for (int c = tid; c < 2048; c += 512) {            // sCT: 64 cols x 256 s
        int col = c >> 5, s8 = c & 31;
        *(bf16x8*)(sCT + col * 264 + s8 * 8) =
            *(const bf16x8*)(ctxT + ((size_t)(b * DIMD) + j * 64 + col) * NS + s8 * 8);
    }
    for (int c = tid; c < NT * 64; c += 512) {         // sQ
        int tt = c >> 6, e = c & 63;
        sQ[c] = qmf[((size_t)tt * NB + b) * DIMD + j * 64 + e];
    }
    // weight slice -> registers (statically indexed): thread (m,cl,q) owns 128 d-values
    int m = tid >> 8, cl = (tid >> 2) & 63, q = tid & 3;
    const __bf16* wp = (m ? wrrT : wrmT) + ((size_t)(j * 64 + cl)) * DIMD + q * 128;
    bf16x8 wreg[16];
#pragma unroll
    for (int u = 0; u < 16; u++) wreg[u] = *(const bf16x8*)(wp + u * 8);

    float wm[8];
#pragma unroll
    for (int u = 0; u < 8; u++) wm[u] = wms[e0 + u];
    if (tid < 64) {
        srm[tid] = brm[j * 64 + tid];            // rm_0 slice (r0 = 0)
        sh[tid]  = tanh_fast(brr[j * 64 + tid]); // h_0 slice
    }
    __syncthreads();

    for (int t = 0; t < NT; t++) {
        // ---- phase A: partial logits over own e-slice (all LDS) ----
        float rq[8];
#pragma unroll
        for (int u = 0; u < 8; u++) rq[u] = srm[i * 8 + u] + sQ[t * 64 + i * 8 + u];
#pragma unroll
        for (int k = 0; k < 4; k++) {
            int s = wave * 32 + k * 8 + g;
            bf16x8 cv = *(const bf16x8*)(sA + s * 72 + i * 8);
            float a = 0.f;
#pragma unroll
            for (int u = 0; u < 8; u++)
                a += tanh_fast((float)cv[u] + rq[u]) * wm[u];
            a += __shfl_xor(a, 1); a += __shfl_xor(a, 2); a += __shfl_xor(a, 4);
            if (i == 0) spart[s] = a;
        }
        __syncthreads();
        __atomic_signal_fence(__ATOMIC_SEQ_CST);
        if (tid < NS)
            __hip_atomic_store(&partials[(b * 8 + j) * NS + tid], spart[tid],
                               __ATOMIC_RELAXED, __HIP_MEMORY_SCOPE_AGENT);
        __atomic_signal_fence(__ATOMIC_SEQ_CST);
        bbar(&ctr[(0 * NT + t) * NB + b]);

        // ---- phase B1: gather partials, softmax, r-slice ----
        {
            int s = tid >> 1, jh = (tid & 1) * 4;
            float a = 0.f;
#pragma unroll
            for (int u = 0; u < 4; u++)
                a += __hip_atomic_load(&partials[(b * 8 + jh + u) * NS + s],
                                       __ATOMIC_RELAXED, __HIP_MEMORY_SCOPE_AGENT);
            sq[tid] = a;
        }
        __syncthreads();
        float ev = 0.f;
        if (tid < NS) { ev = __expf(sq[2 * tid] + sq[2 * tid + 1]); sp[tid] = ev; }
#pragma unroll
        for (int off = 32; off; off >>= 1) ev += __shfl_xor(ev, off);
        if (tid < NS && lane == 0) s4[wave] = ev;
        __syncthreads();
        float inv = 1.f / (s4[0] + s4[1] + s4[2] + s4[3]);
        {
            int cl2 = tid >> 3, q2 = tid & 7;
            const __bf16* cp = sCT + cl2 * 264 + q2 * 32;
            const float* pp = sp + q2 * 32;
            float a = 0.f;
#pragma unroll
            for (int s8 = 0; s8 < 32; s8 += 8) {
                bf16x8 v = *(const bf16x8*)(cp + s8);
#pragma unroll
                for (int u = 0; u < 8; u++) a = fmaf(pp[s8 + u], (float)v[u], a);
            }
            sq[tid] = a;
        }
        __syncthreads();
        if (tid < 64) {
            float a = 0.f;
#pragma unroll
            for (int u = 0; u < 8; u++) a += sq[tid * 8 + u];
            float rv = a * inv + sh[tid];
            if (t == NT - 1) rbuf[b * DIMD + j * 64 + tid] = rv;   // final r
            else
                __hip_atomic_store(&rpub[b * DIMD + j * 64 + tid], rv,
                                   __ATOMIC_RELAXED, __HIP_MEMORY_SCOPE_AGENT);
        }
        __atomic_signal_fence(__ATOMIC_SEQ_CST);
        if (t == NT - 1) break;            // no consumers after last step
        bbar(&ctr[(1 * NT + t) * NB + b]);

        // ---- phase B2: gather r, register-weight matvec -> rm/h (block-local) ----
        sr[tid] = __hip_atomic_load(&rpub[b * DIMD + tid],
                                    __ATOMIC_RELAXED, __HIP_MEMORY_SCOPE_AGENT);
        __syncthreads();
        {
            const float* sv = sr + q * 128;
            float a0 = 0.f, a1 = 0.f;
#pragma unroll
            for (int u = 0; u < 16; u += 2) {
                bf16x8 w0 = wreg[u], w1 = wreg[u + 1];
#pragma unroll
                for (int e = 0; e < 8; e++) {
                    a0 = fmaf(sv[u * 8 + e],     (float)w0[e], a0);
                    a1 = fmaf(sv[u * 8 + 8 + e], (float)w1[e], a1);
                }
            }
            smv[tid] = a0 + a1;
        }
        __syncthreads();
        if (tid < 128) {
            int m2 = tid >> 6, cl3 = tid & 63;
            float a = smv[m2 * 256 + cl3 * 4] + smv[m2 * 256 + cl3 * 4 + 1]
                    + smv[m2 * 256 + cl3 * 4 + 2] + smv[m2 * 256 + cl3 * 4 + 3];
            int col = j * 64 + cl3;
            if (m2 == 0) srm[cl3] = a + brm[col];
            else         sh[cl3]  = tanh_fast(a + brr[col]);
        }
        __syncthreads();
    }
}

// g = r@W_rg + b_rg + qh@W_qg + b_qg   (64 blocks x 256 thr)
__global__ void k_final2(const float* __restrict__ r, const float* __restrict__ qh,
                         const float* __restrict__ Wrg, const float* __restrict__ Wqg,
                         const float* __restrict__ brg, const float* __restrict__ bqg,
                         float* __restrict__ out) {
    int cl = threadIdx.x & 7, b = threadIdx.x >> 3;
    int col = blockIdx.x * 8 + cl;
    const float* rp = r + (size_t)b * DIMD;
    const float* qp = qh + (size_t)b * DIMD;
    float acc = brg[col] + bqg[col];
#pragma unroll 4
    for (int d = 0; d < DIMD; d++)
        acc += rp[d] * Wrg[(size_t)d * DIMD + col] + qp[d] * Wqg[(size_t)d * DIMD + col];
    out[b * DIMD + col] = acc;
}

// ---------------- host ----------------

extern "C" void kernel_launch(void* const* d_in, const int* in_sizes, int n_in,
                              void* d_out, int out_size, void* d_ws, size_t ws_size,
                              hipStream_t stream) {
    const float* ctx_in = (const float*)d_in[0];
    const float* q_in   = (const float*)d_in[1];
    const float* qh     = (const float*)d_in[2];
    const float* img    = (const float*)d_in[3];
    const float* W_fc1  = (const float*)d_in[4];
    const float* b_fc1  = (const float*)d_in[5];
    const float* W_fc2  = (const float*)d_in[6];
    const float* b_fc2  = (const float*)d_in[7];
    const float* W_dm   = (const float*)d_in[8];
    const float* b_dm   = (const float*)d_in[9];
    const float* W_rm   = (const float*)d_in[10];
    const float* b_rm   = (const float*)d_in[11];
    const float* W_qm   = (const float*)d_in[12];
    const float* b_qm   = (const float*)d_in[13];
    const float* W_rr   = (const float*)d_in[14];
    const float* b_rr   = (const float*)d_in[15];
    const float* W_rg   = (const float*)d_in[16];
    const float* b_rg   = (const float*)d_in[17];
    const float* W_qg   = (const float*)d_in[18];
    const float* b_qg   = (const float*)d_in[19];
    const float* W_ms   = (const float*)d_in[20];
    // d_in[21] = b_ms: unused (softmax shift-invariant)

    // workspace layout (~37.7 MB peak; proven budget 38.9 MB)
    char* w = (char*)d_ws;
    __bf16* acat  = (__bf16*)w;  w += (size_t)8192 * 1024 * 2;   // 16.78 MB, dead after g1
    __bf16* qp    = (__bf16*)w;  w += (size_t)1024 * 512 * 2;
    __bf16* wcatT = (__bf16*)w;  w += (size_t)512 * 1024 * 2;
    __bf16* wdmT  = (__bf16*)w;  w += (size_t)512 * 512 * 2;
    __bf16* wqmT  = (__bf16*)w;  w += (size_t)512 * 512 * 2;
    __bf16* wrmT2 = (__bf16*)w;  w += (size_t)512 * 512 * 2;
    __bf16* wrrT2 = (__bf16*)w;  w += (size_t)512 * 512 * 2;
    __bf16* ctxb  = (__bf16*)w;  w += (size_t)8192 * 512 * 2;
    __bf16* ctxdm = (__bf16*)w;  w += (size_t)8192 * 512 * 2;
    // sub-allocate dead acat region (written only after g1 consumed it)
    char* x = (char*)acat;
    __bf16*   ctxT  = (__bf16*)x;    x += (size_t)NB * DIMD * NS * 2;  // 8.39 MB
    float*    qmf   = (float*)x;     x += (size_t)1024 * 512 * 4;      // 2.10 MB
    float*    rpub  = (float*)x;     x += (size_t)NB * DIMD * 4;       // 64 KB
    float*    parts = (float*)x;     x += (size_t)NB * 8 * NS * 4;     // 256 KB
    float*    rbuf  = (float*)x;     x += (size_t)NB * DIMD * 4;       // 64 KB
    unsigned* ctr   = (unsigned*)x;  x += (size_t)2 * NT * NB * 4;     // 8 KB

    // prep
    k_prep_acat<<<8192, 256, 0, stream>>>(ctx_in, img, acat);
    k_cvt_bf16<<<512, 256, 0, stream>>>(q_in, qp, NT * NB * DIMD);
    k_transpose_w6<<<dim3(16, 16, 6), dim3(32, 8), 0, stream>>>(
        W_fc1, W_fc2, W_dm, W_qm, W_rm, W_rr, wcatT, wdmT, wqmT, wrmT2, wrrT2);

    // g1: ctx_cat -> ctxb (consumes acat)
    k_gemm64<<<dim3(128, 8), 256, 0, stream>>>(acat, wcatT, b_fc1, b_fc2, ctxb, 8192, 512, 1024, 0);
    // acat dead: build scan operands in its place
    k_transpose_cb<<<dim3(16, 8, 32), dim3(32, 8), 0, stream>>>(ctxb, ctxT);
    k_gemm64<<<dim3(128, 8), 256, 0, stream>>>(ctxb, wdmT, b_dm, nullptr, ctxdm, 8192, 512, 512, 0);
    k_gemm64<<<dim3(16, 8), 256, 0, stream>>>(qp, wqmT, b_qm, nullptr, qmf, 1024, 512, 512, 1);

    // zero barrier counters (ws is 0xAA-poisoned before every launch)
    hipMemsetAsync(ctr, 0, (size_t)2 * NT * NB * 4, stream);

    // full-machine scan: 256 blocks (8 per batch) x 512 threads
    k_scan<<<256, 512, 0, stream>>>(ctxdm, ctxT, wrmT2, wrrT2, qmf, W_ms,
                                    b_rm, b_rr, parts, rpub, ctr, rbuf);

    k_final2<<<64, 256, 0, stream>>>(rbuf, qh, W_rg, W_qg, b_rg, b_qg, (float*)d_out);
}

// Round 7
// 501.309 us; speedup vs baseline: 4.0401x; 1.5544x over previous
//
#include <hip/hip_runtime.h>
#include <hip/hip_bf16.h>

// Problem dims (fixed by reference): D=512, B=32, S_c=256, S_q(T)=32
#define DIMD 512
#define NB   32
#define NS   256
#define NT   32
// LDS strides chosen for bank-conflict freedom (dword-stride ≡ 1/2 mod 32)
#define SA_STR  66    // ctxdm slice rows (bf16): 132B = 33 dw ≡ 1
#define SCT_STR 258   // ctxT slice rows (bf16): 516B = 129 dw ≡ 1
#define SR_STR  132   // r chunks (fp32): 132 dw ≡ 4 -> q-groups on distinct banks

typedef __bf16 bf16x8 __attribute__((ext_vector_type(8)));
typedef float  f32x4  __attribute__((ext_vector_type(4)));

__device__ __forceinline__ float tanh_fast(float x) {
    float e = __expf(2.f * x);
    return 1.f - 2.f / (e + 1.f);
}

// async global->LDS, 16B per lane; lds dest = wave-uniform base + lane*16
__device__ __forceinline__ void gl_lds16(const __bf16* g, __bf16* l) {
    __builtin_amdgcn_global_load_lds((const __attribute__((address_space(1))) void*)g,
                                     (__attribute__((address_space(3))) void*)l, 16, 0, 0);
}

// ---------------- prep kernels ----------------

// blocks 0..8191: acat rows; blocks 8192..10239: q fp32->bf16
__global__ void k_prep(const float* __restrict__ ctxin, const float* __restrict__ img,
                       const float* __restrict__ qin,
                       __bf16* __restrict__ acat, __bf16* __restrict__ qp) {
    int row = blockIdx.x;
    if (row < 8192) {
        int b = row >> 8, s = row & 255;
        const float* c  = ctxin + ((size_t)s * NB + b) * DIMD;
        const float* im = img   + ((size_t)s * NB + b) * DIMD;
        __bf16* o = acat + (size_t)row * 1024;
        for (int d = threadIdx.x; d < DIMD; d += 256) {
            o[d]       = (__bf16)c[d];
            o[512 + d] = (__bf16)im[d];
        }
    } else {
        int idx = (row - 8192) * 256 + threadIdx.x;   // 2048*256 = 524288 = NT*NB*DIMD
        qp[idx] = (__bf16)qin[idx];
    }
}

// fused transpose of six 512x512 weight matrices (fp32 -> bf16), z selects
__global__ void k_transpose_w6(const float* __restrict__ s0, const float* __restrict__ s1,
                               const float* __restrict__ s2, const float* __restrict__ s3,
                               const float* __restrict__ s4_, const float* __restrict__ s5,
                               __bf16* __restrict__ d01, __bf16* __restrict__ d2,
                               __bf16* __restrict__ d3, __bf16* __restrict__ d4,
                               __bf16* __restrict__ d5) {
    __shared__ float tile[32][33];
    int z = blockIdx.z;
    const float* src = (z == 0) ? s0 : (z == 1) ? s1 : (z == 2) ? s2
                     : (z == 3) ? s3 : (z == 4) ? s4_ : s5;
    __bf16* dst; int stride, off;
    if (z < 2) { dst = d01; stride = 1024; off = z * 512; }
    else {
        dst = (z == 2) ? d2 : (z == 3) ? d3 : (z == 4) ? d4 : d5;
        stride = 512; off = 0;
    }
    int c0 = blockIdx.x * 32, r0 = blockIdx.y * 32;
    int x = threadIdx.x, y = threadIdx.y;   // 32 x 8
#pragma unroll
    for (int k = 0; k < 32; k += 8)
        tile[y + k][x] = src[(size_t)(r0 + y + k) * DIMD + c0 + x];
    __syncthreads();
#pragma unroll
    for (int k = 0; k < 32; k += 8)
        dst[(size_t)(c0 + y + k) * stride + off + r0 + x] = (__bf16)tile[x][y + k];
}

// post-g1 transposes, fused: z<32 -> ctxT per-batch transpose (y<8 active);
// z==32/33 -> W_rg/W_qg fp32->bf16 transpose
__global__ void k_post_t(const __bf16* __restrict__ ctxb, __bf16* __restrict__ ctxT,
                         const float* __restrict__ Wrg, const float* __restrict__ Wqg,
                         __bf16* __restrict__ wrgT, __bf16* __restrict__ wqgT) {
    int z = blockIdx.z;
    int x = threadIdx.x, y = threadIdx.y;   // 32 x 8
    if (z < 32) {
        if (blockIdx.y >= 8) return;
        __shared__ __bf16 tile[32][33];
        int c0 = blockIdx.x * 32, s0 = blockIdx.y * 32;
        const __bf16* S = ctxb + (size_t)z * NS * DIMD;
        __bf16* D = ctxT + (size_t)z * DIMD * NS;
#pragma unroll
        for (int k = 0; k < 32; k += 8)
            tile[y + k][x] = S[(size_t)(s0 + y + k) * DIMD + c0 + x];
        __syncthreads();
#pragma unroll
        for (int k = 0; k < 32; k += 8)
            D[(size_t)(c0 + y + k) * NS + s0 + x] = tile[x][y + k];
    } else {
        __shared__ float tf[32][33];
        const float* src = (z == 32) ? Wrg : Wqg;
        __bf16* dst = (z == 32) ? wrgT : wqgT;
        int c0 = blockIdx.x * 32, r0 = blockIdx.y * 32;
#pragma unroll
        for (int k = 0; k < 32; k += 8)
            tf[y + k][x] = src[(size_t)(r0 + y + k) * DIMD + c0 + x];
        __syncthreads();
#pragma unroll
        for (int k = 0; k < 32; k += 8)
            dst[(size_t)(c0 + y + k) * DIMD + r0 + x] = (__bf16)tf[x][y + k];
    }
}

// ---------------- LDS-staged bf16 MFMA GEMM, 64x64 tile ----------------
__global__ void k_gemm64(const __bf16* __restrict__ A, const __bf16* __restrict__ BT,
                         const float* __restrict__ bias1, const float* __restrict__ bias2,
                         void* __restrict__ out, int M, int N, int K, int out_f32) {
    __shared__ __bf16 As[64 * 64];
    __shared__ __bf16 Bs[64 * 64];
    int tid = threadIdx.x, wave = tid >> 6, lane = tid & 63;
    int wm = wave >> 1, wn = wave & 1;
    int m0 = blockIdx.x * 64, n0 = blockIdx.y * 64;
    int lr = lane & 15, lq = lane >> 4;

    f32x4 acc[2][2];
#pragma unroll
    for (int i = 0; i < 2; i++)
#pragma unroll
        for (int j = 0; j < 2; j++) acc[i][j] = (f32x4){0.f, 0.f, 0.f, 0.f};

    int g0 = (wave * 2 + 0) * 64 + lane;
    int g1 = (wave * 2 + 1) * 64 + lane;
    int r0_ = g0 >> 3, c0_ = g0 & 7;
    int r1_ = g1 >> 3, c1_ = g1 & 7;
    __bf16* la0 = As + (wave * 2 + 0) * 512;
    __bf16* la1 = As + (wave * 2 + 1) * 512;
    __bf16* lb0 = Bs + (wave * 2 + 0) * 512;
    __bf16* lb1 = Bs + (wave * 2 + 1) * 512;

    for (int kk = 0; kk < K; kk += 64) {
        gl_lds16(A  + (size_t)(m0 + r0_) * K + kk + c0_ * 8, la0);
        gl_lds16(A  + (size_t)(m0 + r1_) * K + kk + c1_ * 8, la1);
        gl_lds16(BT + (size_t)(n0 + r0_) * K + kk + c0_ * 8, lb0);
        gl_lds16(BT + (size_t)(n0 + r1_) * K + kk + c1_ * 8, lb1);
        __syncthreads();
#pragma unroll
        for (int k2 = 0; k2 < 64; k2 += 32) {
            bf16x8 af[2], bfv[2];
#pragma unroll
            for (int i = 0; i < 2; i++)
                af[i] = *(const bf16x8*)(As + (wm * 32 + i * 16 + lr) * 64 + k2 + lq * 8);
#pragma unroll
            for (int j = 0; j < 2; j++)
                bfv[j] = *(const bf16x8*)(Bs + (wn * 32 + j * 16 + lr) * 64 + k2 + lq * 8);
#pragma unroll
            for (int i = 0; i < 2; i++)
#pragma unroll
                for (int j = 0; j < 2; j++)
                    acc[i][j] = __builtin_amdgcn_mfma_f32_16x16x32_bf16(af[i], bfv[j], acc[i][j], 0, 0, 0);
        }
        __syncthreads();
    }

#pragma unroll
    for (int i = 0; i < 2; i++)
#pragma unroll
        for (int j = 0; j < 2; j++) {
            int col = n0 + wn * 32 + j * 16 + lr;
            float bs = bias1[col] + (bias2 ? bias2[col] : 0.f);
#pragma unroll
            for (int r = 0; r < 4; r++) {
                int row = m0 + wm * 32 + i * 16 + lq * 4 + r;
                float v = acc[i][j][r] + bs;
                if (out_f32) ((float*)out)[(size_t)row * N + col] = v;
                else         ((__bf16*)out)[(size_t)row * N + col] = (__bf16)v;
            }
        }
}

// ---------------- scan: 8 blocks/batch, per-block flag sync, on-chip state ----------------

// Flag barrier: each block STORES a monotone phase value to its own 64B-spaced
// flag (no RMW -> no cacheline serialization); lanes 0-7 of wave 0 poll all 8
// flags in parallel. No acquire/release fences (they emit buffer_inv/wbl2 ->
// round-3's 23us/barrier); RELAXED uncached atomics + per-wave vmcnt drain at
// __syncthreads give the ordering (proven rounds 5/6).
__device__ __forceinline__ void bflag(unsigned* fb, int j, unsigned tgt) {
    __syncthreads();                       // all waves' stores drained (vmcnt 0)
    if (threadIdx.x == 0) {
        __atomic_signal_fence(__ATOMIC_SEQ_CST);
        __builtin_amdgcn_s_waitcnt(0x0F70);   // vmcnt(0) belt-and-suspenders
        __atomic_signal_fence(__ATOMIC_SEQ_CST);
        __hip_atomic_store(fb + j * 16, tgt, __ATOMIC_RELAXED, __HIP_MEMORY_SCOPE_AGENT);
    }
    if (threadIdx.x < 8) {
        while (__hip_atomic_load(fb + threadIdx.x * 16, __ATOMIC_RELAXED,
                                 __HIP_MEMORY_SCOPE_AGENT) < tgt)
            __builtin_amdgcn_s_sleep(1);
    }
    __syncthreads();
}

// grid 256 = 32 batches x 8 e-slices; block 512 threads (8 waves), 1 block/CU.
// All loop-invariant data staged once (LDS + weight regs); per-step global
// traffic = partials/r relaxed atomics only.
__global__ __launch_bounds__(512, 2) void k_scan(
    const __bf16* __restrict__ ctxdm,  // [b*256+s][512]
    const __bf16* __restrict__ ctxT,   // [b][c][s]
    const __bf16* __restrict__ wrmT,   // [c][d]
    const __bf16* __restrict__ wrrT,   // [c][d]
    const float* __restrict__ qmf,     // [t*32+b][512]
    const float* __restrict__ wms, const float* __restrict__ brm,
    const float* __restrict__ brr,
    float* partials,                   // [b][8][256]
    float* rpub,                       // [b][512]
    unsigned* flags,                   // [256][16], zeroed
    float* __restrict__ rbuf) {
    int bid = blockIdx.x;
    int b = bid >> 3, j = bid & 7;
    int tid = threadIdx.x, wave = tid >> 6, lane = tid & 63;
    int g = lane >> 3, i = lane & 7;       // s-subgroup, e-chunk

    __shared__ __bf16 sA[256 * SA_STR];    // 33.8 KB
    __shared__ __bf16 sCT[64 * SCT_STR];   // 33.0 KB
    __shared__ float  sQ[NT * 64];         //  8 KB
    __shared__ float  spart[NS];
    __shared__ float  sp[NS];
    __shared__ float  sq[512];
    __shared__ float  s4[4];
    __shared__ float  sps[8 * 68];         // B1 per-wave partials (stride 68)
    __shared__ float  srm[64], sh[64];
    __shared__ float  sr4[4 * SR_STR];     // r in 4 padded chunks
    __shared__ float  smv[512];

    unsigned* fb = flags + b * 8 * 16;

    // ---- one-time staging ----
    for (int c = tid; c < 2048; c += 512) {            // sA: 256 rows x 64 e
        int row = c >> 3, c8 = c & 7;
        *(bf16x8*)(sA + row * SA_STR + c8 * 8) =
            *(const bf16x8*)(ctxdm + ((size_t)(b * NS + row)) * DIMD + j * 64 + c8 * 8);
    }
    for (int c = tid; c < 2048; c += 512) {            // sCT: 64 cols x 256 s
        int col = c >> 5, s8 = c & 31;
        *(bf16x8*)(sCT + col * SCT_STR + s8 * 8) =
            *(const bf16x8*)(ctxT + ((size_t)(b * DIMD) + j * 64 + col) * NS + s8 * 8);
    }
    for (int c = tid; c < NT * 64; c += 512) {         // sQ
        int tt = c >> 6, e = c & 63;
        sQ[c] = qmf[((size_t)tt * NB + b) * DIMD + j * 64 + e];
    }
    // weight slice -> registers: thread (m,cl,q) owns d in [q*128,(q+1)*128)
    int m = tid >> 8, cl = (tid >> 2) & 63, q = tid & 3;
    const __bf16* wp = (m ? wrrT : wrmT) + ((size_t)(j * 64 + cl)) * DIMD + q * 128;
    bf16x8 wreg[16];
#pragma unroll
    for (int u = 0; u < 16; u++) wreg[u] = *(const bf16x8*)(wp + u * 8);

    float wm[8];
#pragma unroll
    for (int u = 0; u < 8; u++) wm[u] = wms[j * 64 + i * 8 + u];
    if (tid < 64) {
        srm[tid] = brm[j * 64 + tid];            // rm_0 slice (r0 = 0)
        sh[tid]  = tanh_fast(brr[j * 64 + tid]); // h_0 slice
    }
    __syncthreads();

    unsigned ph = 1;
    for (int t = 0; t < NT; t++) {
        // ---- phase A: partial logits over own e-slice (all LDS) ----
        float rq[8];
#pragma unroll
        for (int u = 0; u < 8; u++) rq[u] = srm[i * 8 + u] + sQ[t * 64 + i * 8 + u];
#pragma unroll
        for (int k = 0; k < 4; k++) {
            int s = wave * 32 + k * 8 + g;
            bf16x8 cv = *(const bf16x8*)(sA + s * SA_STR + i * 8);
            float a = 0.f;
#pragma unroll
            for (int u = 0; u < 8; u++)
                a += tanh_fast((float)cv[u] + rq[u]) * wm[u];
            a += __shfl_xor(a, 1); a += __shfl_xor(a, 2); a += __shfl_xor(a, 4);
            if (i == 0) spart[s] = a;
        }
        __syncthreads();
        if (tid < NS)
            __hip_atomic_store(&partials[(b * 8 + j) * NS + tid], spart[tid],
                               __ATOMIC_RELAXED, __HIP_MEMORY_SCOPE_AGENT);
        bflag(fb, j, ph); ph++;

        // ---- phase B1: gather partials, softmax, weighted ctx sum -> r-slice ----
        {
            int s = tid >> 1, jh = (tid & 1) * 4;
            float a = 0.f;
#pragma unroll
            for (int u = 0; u < 4; u++)
                a += __hip_atomic_load(&partials[(b * 8 + jh + u) * NS + s],
                                       __ATOMIC_RELAXED, __HIP_MEMORY_SCOPE_AGENT);
            sq[tid] = a;
        }
        __syncthreads();
        float ev = 0.f;
        if (tid < NS) { ev = __expf(sq[2 * tid] + sq[2 * tid + 1]); sp[tid] = ev; }
#pragma unroll
        for (int off = 32; off; off >>= 1) ev += __shfl_xor(ev, off);
        if (tid < NS && lane == 0) s4[wave] = ev;
        __syncthreads();
        float inv = 1.f / (s4[0] + s4[1] + s4[2] + s4[3]);
        {
            // wave = s-chunk, lane = col: per-lane linear LDS streams (2-way max)
            const __bf16* cp = sCT + lane * SCT_STR + wave * 32;
            const float* pp = sp + wave * 32;
            float a = 0.f;
#pragma unroll
            for (int k = 0; k < 32; k += 8) {
                bf16x8 v = *(const bf16x8*)(cp + k);
#pragma unroll
                for (int u = 0; u < 8; u++) a = fmaf(pp[k + u], (float)v[u], a);
            }
            sps[wave * 68 + lane] = a;
        }
        __syncthreads();
        if (tid < 64) {
            float a = 0.f;
#pragma unroll
            for (int w2 = 0; w2 < 8; w2++) a += sps[w2 * 68 + tid];
            float rv = a * inv + sh[tid];
            if (t == NT - 1) rbuf[b * DIMD + j * 64 + tid] = rv;   // final r
            else
                __hip_atomic_store(&rpub[b * DIMD + j * 64 + tid], rv,
                                   __ATOMIC_RELAXED, __HIP_MEMORY_SCOPE_AGENT);
        }
        if (t == NT - 1) break;            // no consumers after last step
        bflag(fb, j, ph); ph++;

        // ---- phase B2: gather r, register-weight matvec -> rm/h (block-local) ----
        sr4[(tid >> 7) * SR_STR + (tid & 127)] =
            __hip_atomic_load(&rpub[b * DIMD + tid], __ATOMIC_RELAXED, __HIP_MEMORY_SCOPE_AGENT);
        __syncthreads();
        {
            const float* sv = sr4 + q * SR_STR;   // q-groups land on distinct banks
            float a0 = 0.f, a1 = 0.f;
#pragma unroll
            for (int u = 0; u < 16; u += 2) {
                bf16x8 w0 = wreg[u], w1 = wreg[u + 1];
#pragma unroll
                for (int e = 0; e < 8; e++) {
                    a0 = fmaf(sv[u * 8 + e],     (float)w0[e], a0);
                    a1 = fmaf(sv[u * 8 + 8 + e], (float)w1[e], a1);
                }
            }
            smv[tid] = a0 + a1;
        }
        __syncthreads();
        if (tid < 128) {
            int m2 = tid >> 6, cl3 = tid & 63;
            float a = smv[m2 * 256 + cl3 * 4] + smv[m2 * 256 + cl3 * 4 + 1]
                    + smv[m2 * 256 + cl3 * 4 + 2] + smv[m2 * 256 + cl3 * 4 + 3];
            int col = j * 64 + cl3;
            if (m2 == 0) srm[cl3] = a + brm[col];
            else         sh[cl3]  = tanh_fast(a + brr[col]);
        }
        __syncthreads();
    }
}

// g = r@W_rg + b_rg + qh@W_qg + b_qg  (bf16 [col][d] weights, contiguous reads)
__global__ void k_final2(const float* __restrict__ r, const float* __restrict__ qh,
                         const __bf16* __restrict__ wrgT, const __bf16* __restrict__ wqgT,
                         const float* __restrict__ brg, const float* __restrict__ bqg,
                         float* __restrict__ out) {
    int clx = threadIdx.x & 7, b = threadIdx.x >> 3;
    int col = blockIdx.x * 8 + clx;
    const __bf16* w1 = wrgT + (size_t)col * DIMD;
    const __bf16* w2 = wqgT + (size_t)col * DIMD;
    const float* rp = r + (size_t)b * DIMD;
    const float* qp = qh + (size_t)b * DIMD;
    float acc = brg[col] + bqg[col];
#pragma unroll 4
    for (int d = 0; d < DIMD; d += 8) {
        bf16x8 a = *(const bf16x8*)(w1 + d);
        bf16x8 c = *(const bf16x8*)(w2 + d);
#pragma unroll
        for (int u = 0; u < 8; u++)
            acc += rp[d + u] * (float)a[u] + qp[d + u] * (float)c[u];
    }
    out[b * DIMD + col] = acc;
}

// ---------------- host ----------------

extern "C" void kernel_launch(void* const* d_in, const int* in_sizes, int n_in,
                              void* d_out, int out_size, void* d_ws, size_t ws_size,
                              hipStream_t stream) {
    const float* ctx_in = (const float*)d_in[0];
    const float* q_in   = (const float*)d_in[1];
    const float* qh     = (const float*)d_in[2];
    const float* img    = (const float*)d_in[3];
    const float* W_fc1  = (const float*)d_in[4];
    const float* b_fc1  = (const float*)d_in[5];
    const float* W_fc2  = (const float*)d_in[6];
    const float* b_fc2  = (const float*)d_in[7];
    const float* W_dm   = (const float*)d_in[8];
    const float* b_dm   = (const float*)d_in[9];
    const float* W_rm   = (const float*)d_in[10];
    const float* b_rm   = (const float*)d_in[11];
    const float* W_qm   = (const float*)d_in[12];
    const float* b_qm   = (const float*)d_in[13];
    const float* W_rr   = (const float*)d_in[14];
    const float* b_rr   = (const float*)d_in[15];
    const float* W_rg   = (const float*)d_in[16];
    const float* b_rg   = (const float*)d_in[17];
    const float* W_qg   = (const float*)d_in[18];
    const float* b_qg   = (const float*)d_in[19];
    const float* W_ms   = (const float*)d_in[20];
    // d_in[21] = b_ms: unused (softmax shift-invariant)

    // workspace layout (main chain ~37.7 MB; scan/x-region aliases dead acat)
    char* w = (char*)d_ws;
    __bf16* acat  = (__bf16*)w;  w += (size_t)8192 * 1024 * 2;   // 16.78 MB, dead after g1
    __bf16* qp    = (__bf16*)w;  w += (size_t)1024 * 512 * 2;
    __bf16* wcatT = (__bf16*)w;  w += (size_t)512 * 1024 * 2;
    __bf16* wdmT  = (__bf16*)w;  w += (size_t)512 * 512 * 2;
    __bf16* wqmT  = (__bf16*)w;  w += (size_t)512 * 512 * 2;
    __bf16* wrmT2 = (__bf16*)w;  w += (size_t)512 * 512 * 2;
    __bf16* wrrT2 = (__bf16*)w;  w += (size_t)512 * 512 * 2;
    __bf16* ctxb  = (__bf16*)w;  w += (size_t)8192 * 512 * 2;
    __bf16* ctxdm = (__bf16*)w;  w += (size_t)8192 * 512 * 2;
    // sub-allocate dead acat region (written only after g1 consumed it)
    char* x = (char*)acat;
    __bf16*   ctxT  = (__bf16*)x;    x += (size_t)NB * DIMD * NS * 2;  // 8.39 MB
    float*    qmf   = (float*)x;     x += (size_t)1024 * 512 * 4;      // 2.10 MB
    __bf16*   wrgT  = (__bf16*)x;    x += (size_t)512 * 512 * 2;       // 0.52 MB
    __bf16*   wqgT  = (__bf16*)x;    x += (size_t)512 * 512 * 2;       // 0.52 MB
    float*    rpub  = (float*)x;     x += (size_t)NB * DIMD * 4;       // 64 KB
    float*    parts = (float*)x;     x += (size_t)NB * 8 * NS * 4;     // 256 KB
    float*    rbuf  = (float*)x;     x += (size_t)NB * DIMD * 4;       // 64 KB
    unsigned* flags = (unsigned*)x;  x += (size_t)256 * 16 * 4;        // 16 KB

    // prep (acat + qp), 6 pre-g1 weight transposes
    k_prep<<<10240, 256, 0, stream>>>(ctx_in, img, q_in, acat, qp);
    k_transpose_w6<<<dim3(16, 16, 6), dim3(32, 8), 0, stream>>>(
        W_fc1, W_fc2, W_dm, W_qm, W_rm, W_rr, wcatT, wdmT, wqmT, wrmT2, wrrT2);

    // g1: ctx_cat -> ctxb (consumes acat)
    k_gemm64<<<dim3(128, 8), 256, 0, stream>>>(acat, wcatT, b_fc1, b_fc2, ctxb, 8192, 512, 1024, 0);
    // acat dead: ctxT + W_rg/W_qg transposes into its place (fused)
    k_post_t<<<dim3(16, 16, 34), dim3(32, 8), 0, stream>>>(ctxb, ctxT, W_rg, W_qg, wrgT, wqgT);
    k_gemm64<<<dim3(128, 8), 256, 0, stream>>>(ctxb, wdmT, b_dm, nullptr, ctxdm, 8192, 512, 512, 0);
    k_gemm64<<<dim3(16, 8), 256, 0, stream>>>(qp, wqmT, b_qm, nullptr, qmf, 1024, 512, 512, 1);

    // zero flags (ws is 0xAA-poisoned before every launch)
    hipMemsetAsync(flags, 0, (size_t)256 * 16 * 4, stream);

    // full-machine scan: 256 blocks (8 per batch) x 512 threads
    k_scan<<<256, 512, 0, stream>>>(ctxdm, ctxT, wrmT2, wrrT2, qmf, W_ms,
                                    b_rm, b_rr, parts, rpub, flags, rbuf);

    k_final2<<<64, 256, 0, stream>>>(rbuf, qh, wrgT, wqgT, b_rg, b_qg, (float*)d_out);
}